// Round 12
// baseline (217.492 us; speedup 1.0000x reference)
//
#include <hip/hip_runtime.h>
#include <hip/hip_bf16.h>
#include <cstdint>
#include <cstddef>

#define S_LEN 2048
#define D_MODEL 1024
#define N_HEADS 16
#define DEPTH 64
#define BATCH 4

#define GLOBAL_AS __attribute__((address_space(1)))
#define LDS_AS __attribute__((address_space(3)))

typedef __attribute__((ext_vector_type(4))) float f32x4;
typedef __attribute__((ext_vector_type(8))) short bf16x8;
typedef __attribute__((ext_vector_type(4))) unsigned short us4;
typedef __attribute__((ext_vector_type(8))) unsigned short us8;

__device__ __forceinline__ unsigned short f2bf(float f) {
  unsigned int u = __builtin_bit_cast(unsigned int, f);
  u += 0x7FFFu + ((u >> 16) & 1u);   // round-to-nearest-even
  return (unsigned short)(u >> 16);
}

__device__ __forceinline__ unsigned short f2bf_hw(float f) {
  return __builtin_bit_cast(unsigned short, __float2bfloat16(f));
}

// ---------------------------------------------------------------------------
// Fused weight transpose + scale + fp32 -> bf16 cast for all 4 weights.
// ---------------------------------------------------------------------------
struct TCArgs {
  const float* W[4];
  unsigned short* Wt[4];
  float scale[4];
};

__global__ __launch_bounds__(256) void transpose_cast4(TCArgs a, int N) {
  __shared__ float tile[32][33];
  int z = blockIdx.z;
  const float* W = a.W[z];
  unsigned short* Wt = a.Wt[z];
  float scale = a.scale[z];
  int bx = blockIdx.x * 32;
  int by = blockIdx.y * 32;
  int tx = threadIdx.x, ty = threadIdx.y;  // 32 x 8
#pragma unroll
  for (int i = 0; i < 4; ++i)
    tile[ty + i * 8][tx] = W[(size_t)(by + ty + i * 8) * N + bx + tx];
  __syncthreads();
#pragma unroll
  for (int i = 0; i < 4; ++i)
    Wt[(size_t)(bx + ty + i * 8) * N + by + tx] = f2bf(tile[tx][ty + i * 8] * scale);
}

// ---------------------------------------------------------------------------
// fp32 -> bf16 cast of q, k, v (enables global_load_lds staging in gemm8).
// grid 4096 x 256 threads, 8 elems/thread/tensor, fully coalesced.
// ---------------------------------------------------------------------------
__global__ __launch_bounds__(256) void cast3_bf16(const float* __restrict__ q,
                                                  const float* __restrict__ k,
                                                  const float* __restrict__ v,
                                                  unsigned short* __restrict__ qb,
                                                  unsigned short* __restrict__ kb,
                                                  unsigned short* __restrict__ vb) {
  size_t i = ((size_t)blockIdx.x * 256 + threadIdx.x) * 8;
  f32x4 x0, x1;
  us8 o;
  x0 = *(const f32x4*)(q + i); x1 = *(const f32x4*)(q + i + 4);
#pragma unroll
  for (int e = 0; e < 4; ++e) { o[e] = f2bf_hw(x0[e]); o[e + 4] = f2bf_hw(x1[e]); }
  *(us8*)(qb + i) = o;
  x0 = *(const f32x4*)(k + i); x1 = *(const f32x4*)(k + i + 4);
#pragma unroll
  for (int e = 0; e < 4; ++e) { o[e] = f2bf_hw(x0[e]); o[e + 4] = f2bf_hw(x1[e]); }
  *(us8*)(kb + i) = o;
  x0 = *(const f32x4*)(v + i); x1 = *(const f32x4*)(v + i + 4);
#pragma unroll
  for (int e = 0; e < 4; ++e) { o[e] = f2bf_hw(x0[e]); o[e + 4] = f2bf_hw(x1[e]); }
  *(us8*)(vb + i) = o;
}

// ---------------------------------------------------------------------------
// Per-head V transpose: Vp [B,S,D] bf16 -> Vt [B*H][DEPTH][S] bf16
// ---------------------------------------------------------------------------
__global__ __launch_bounds__(256) void transpose_v(const unsigned short* __restrict__ Vp,
                                                   unsigned short* __restrict__ Vt) {
  __shared__ unsigned short tile[64][72];
  int tid = threadIdx.x;
  int sb = blockIdx.x;
  int bh = blockIdx.y;
  int b = bh >> 4, h = bh & 15;
  int s0 = sb * 64;
#pragma unroll
  for (int rep = 0; rep < 2; ++rep) {
    int idx = rep * 256 + tid;
    int r = idx >> 3, c8 = idx & 7;
    us8 v = *(const us8*)(Vp + (size_t)(b * S_LEN + s0 + r) * D_MODEL + h * DEPTH + c8 * 8);
#pragma unroll
    for (int e = 0; e < 8; ++e) tile[c8 * 8 + e][r] = v[e];
  }
  __syncthreads();
#pragma unroll
  for (int rep = 0; rep < 2; ++rep) {
    int idx = rep * 256 + tid;
    int d = idx >> 3, c8 = idx & 7;
    us8 v = *(const us8*)&tile[d][c8 * 8];
    *(us8*)(Vt + ((size_t)(bh * DEPTH + d)) * S_LEN + s0 + c8 * 8) = v;
  }
}

// ---------------------------------------------------------------------------
// 8-phase GEMM (T3+T4+T5): C[M][N] = A[M][K] @ Bt[N][K]^T + bias*bscale.
// BM=256, BN=128, BK=64, 8 waves (4M x 2N -> 64x64 per wave), 512 thr.
// Both operands via global_load_lds (16B) into double-buffered LINEAR LDS
// (96 KB; swizzle deferred — m198 proves linear-LDS 8-phase >= 1167 TF).
// Iteration = 2 K-tiles (buf0 tile t0, buf1 tile t1), 8 phases, each:
// {ds_read subtile | issue 1 staging unit} -> barrier -> MFMA quad ->
// [counted vmcnt at ph4/ph8 — NEVER 0 in-loop] -> barrier.
// Staging schedule (unit = 2 gloads/thread = 16 KB):
//   ph1: A-half0(buf1)<-t1   ph2: A-half1(buf1)<-t1   ph3: B(buf0)<-t0+2
//   ph4: A-half0(buf0)<-t0+2 [vmcnt(4)]               ph5: A-half1(buf0)<-t0+2
//   ph6: -                   ph7: B(buf1)<-t1+2       ph8: [vmcnt(2)]
// Free-time proof: A(buf) last ds_read at its ph3/ph7; B(buf) at ph2/ph6 —
// every staging is issued after the closing barrier of its region's last
// reader. vmcnt(4)@ph4 drains everything buf1 needs for ph5-8; vmcnt(2)@ph8
// drains everything buf0 needs for next ph1-4 (in-order vmcnt retirement).
// Grid: exactly 256 blocks (1/CU) per dispatch; XCD-bijective remap.
// ---------------------------------------------------------------------------
template <bool OUT_F32>
__global__ __launch_bounds__(512) void gemm8(const unsigned short* __restrict__ A,
                                             const unsigned short* __restrict__ Bt,
                                             const float* __restrict__ bias,
                                             float bscale,
                                             void* __restrict__ Cptr,
                                             int M, int N, int K) {
  __shared__ unsigned short smem[49152];  // [2 bufs][A 256x64 | B 128x64]

  const int tid = threadIdx.x;
  const int wave = tid >> 6, lane = tid & 63;
  const int l15 = lane & 15, lg = lane >> 4;
  const int wm = wave >> 1, wn = wave & 1;

  int bid = blockIdx.x;                       // 256 blocks
  int wk = ((bid & 7) << 5) | (bid >> 3);     // bijective XCD remap (256%8==0)
  int mi = wk >> 3, nj = wk & 7;              // 32 M-tiles x 8 N-tiles
  const int row0 = mi * 256, col0 = nj * 128;

  const unsigned short* Ab = A + (size_t)row0 * K;
  const unsigned short* Bb = Bt + (size_t)col0 * K;

  f32x4 acc[4][4] = {};
  bf16x8 aF[2][2];        // current a-quadrant: 2 M-frags x 2 kk
  bf16x8 bF[2][2][2];     // both b-quadrants kept: [b][nf][kk]

  const int nk = K >> 6;  // 16

  auto bar = [&]() {
    asm volatile("" ::: "memory");
    __builtin_amdgcn_s_barrier();
    asm volatile("" ::: "memory");
  };
  auto stageA = [&](int buf, int h, int t) {
#pragma unroll
    for (int j = 0; j < 2; ++j) {
      int c = j * 512 + tid;
      __builtin_amdgcn_global_load_lds(
          (const GLOBAL_AS void*)(Ab + (size_t)(h * 128 + (c >> 3)) * K + t * 64 + (c & 7) * 8),
          (LDS_AS void*)(&smem[buf * 24576 + h * 8192 + c * 8]), 16, 0, 0);
    }
  };
  auto stageB = [&](int buf, int t) {
#pragma unroll
    for (int j = 0; j < 2; ++j) {
      int c = j * 512 + tid;
      __builtin_amdgcn_global_load_lds(
          (const GLOBAL_AS void*)(Bb + (size_t)(c >> 3) * K + t * 64 + (c & 7) * 8),
          (LDS_AS void*)(&smem[buf * 24576 + 16384 + c * 8]), 16, 0, 0);
    }
  };
  auto readA = [&](int buf, int a) {
#pragma unroll
    for (int mfi = 0; mfi < 2; ++mfi)
#pragma unroll
      for (int kk = 0; kk < 2; ++kk) {
        int row = wm * 64 + (a * 2 + mfi) * 16 + l15;
        aF[mfi][kk] = *(const bf16x8*)&smem[buf * 24576 + row * 64 + kk * 32 + lg * 8];
      }
  };
  auto readB = [&](int buf, int b) {
#pragma unroll
    for (int nfi = 0; nfi < 2; ++nfi)
#pragma unroll
      for (int kk = 0; kk < 2; ++kk) {
        int row = wn * 64 + (b * 2 + nfi) * 16 + l15;
        bF[b][nfi][kk] = *(const bf16x8*)&smem[buf * 24576 + 16384 + row * 64 + kk * 32 + lg * 8];
      }
  };
  auto quad = [&](int a, int b) {
    __builtin_amdgcn_s_setprio(1);
#pragma unroll
    for (int mfi = 0; mfi < 2; ++mfi)
#pragma unroll
      for (int nfi = 0; nfi < 2; ++nfi)
#pragma unroll
        for (int kk = 0; kk < 2; ++kk)
          acc[a * 2 + mfi][b * 2 + nfi] = __builtin_amdgcn_mfma_f32_16x16x32_bf16(
              aF[mfi][kk], bF[b][nfi][kk], acc[a * 2 + mfi][b * 2 + nfi], 0, 0, 0);
    __builtin_amdgcn_s_setprio(0);
  };

  // ---- prologue: tile0 fully + tile1's B; allow tile1-B to keep flying ----
  stageB(0, 0);
  stageA(0, 0, 0);
  stageA(0, 1, 0);
  stageB(1, 1);
  asm volatile("s_waitcnt vmcnt(2)" ::: "memory");
  bar();

  for (int i2 = 0; i2 < nk / 2; ++i2) {
    int t0 = 2 * i2, t1 = t0 + 1;
    bool s2 = (t0 + 2) < nk, s3 = (t1 + 2) < nk;
    // ph1
    readA(0, 0); readB(0, 0);
    stageA(1, 0, t1);
    bar(); quad(0, 0); bar();
    // ph2
    readB(0, 1);
    stageA(1, 1, t1);
    bar(); quad(0, 1); bar();
    // ph3
    readA(0, 1);
    if (s2) stageB(0, t0 + 2);
    bar(); quad(1, 0); bar();
    // ph4
    if (s2) stageA(0, 0, t0 + 2);
    bar(); quad(1, 1);
    asm volatile("s_waitcnt vmcnt(4)" ::: "memory");
    bar();
    // ph5
    readA(1, 0); readB(1, 0);
    if (s2) stageA(0, 1, t0 + 2);
    bar(); quad(0, 0); bar();
    // ph6
    readB(1, 1);
    bar(); quad(0, 1); bar();
    // ph7
    readA(1, 1);
    if (s3) stageB(1, t1 + 2);
    bar(); quad(1, 0); bar();
    // ph8
    quad(1, 1);
    asm volatile("s_waitcnt vmcnt(2)" ::: "memory");
    bar();
  }

  // ---- epilogue ----
#pragma unroll
  for (int mf = 0; mf < 4; ++mf)
#pragma unroll
    for (int nf = 0; nf < 4; ++nf) {
      int col = col0 + wn * 64 + nf * 16 + l15;
      float bv = bias[col] * bscale;
#pragma unroll
      for (int r = 0; r < 4; ++r) {
        int row = row0 + wm * 64 + mf * 16 + lg * 4 + r;
        float v = acc[mf][nf][r] + bv;
        if constexpr (OUT_F32)
          ((float*)Cptr)[(size_t)row * N + col] = v;
        else
          ((unsigned short*)Cptr)[(size_t)row * N + col] = f2bf(v);
      }
    }
}

// ---------------------------------------------------------------------------
// Causal flash attention (r9 form verbatim — best measured config).
// Q pre-scaled by 0.125*log2(e); NO-MAX exp2 softmax; l via ones-MFMA.
// Single-buffered K/V^T, two barriers/step, T14 reg prefetch. Plain bounds.
// ---------------------------------------------------------------------------
__global__ __launch_bounds__(512) void attn_kernel(const unsigned short* __restrict__ Qp,
                                                   const unsigned short* __restrict__ Kp,
                                                   const unsigned short* __restrict__ Vt,
                                                   unsigned short* __restrict__ Op) {
  __shared__ unsigned short k_lds[64][76];
  __shared__ unsigned short vt_lds[64][76];   // [d][k]
  __shared__ unsigned short p_lds[8][16][76];

  int tid = threadIdx.x;
  int w = tid >> 6, lane = tid & 63;
  int l15 = lane & 15, lg = lane >> 4;

  int bid = blockIdx.x;                    // 0..511
  int swz = (bid & 7) * 64 + (bid >> 3);   // bijective (512 % 8 == 0)
  int pairIdx = swz & 7;                   // 0..7
  int bh = swz >> 3;                       // 0..63 (8 bh per XCD)
  int b = bh >> 4, h = bh & 15;

  const unsigned short* Kbase = Kp + (size_t)b * S_LEN * D_MODEL + h * DEPTH;
  const unsigned short* Vbase = Vt + (size_t)bh * DEPTH * S_LEN;

  bool stageV = (tid >= 256);
  int st = tid & 255;
  int r = st >> 2, cb = (st & 3) * 16;
  const unsigned short* srow = stageV ? (Vbase + (size_t)r * S_LEN + cb)
                                      : (Kbase + (size_t)r * D_MODEL + cb);
  const size_t sstep = stageV ? 64 : (size_t)64 * D_MODEL;

  bf16x8 ones;
#pragma unroll
  for (int e = 0; e < 8; ++e) ones[e] = (short)0x3F80;

  for (int half = 0; half < 2; ++half) {
    int t = (half == 0) ? pairIdx : (15 - pairIdx);
    int q0 = t * 128;
    int nkv = 2 * t + 2;
    int q0w = q0 + w * 16;

    const unsigned short* qp =
        Qp + ((size_t)(b * S_LEN + q0 + w * 16 + l15)) * D_MODEL + h * DEPTH;
    bf16x8 qf0 = *(const bf16x8*)(qp + lg * 8);
    bf16x8 qf1 = *(const bf16x8*)(qp + 32 + lg * 8);

    f32x4 acc_l = (f32x4){0.f, 0.f, 0.f, 0.f};
    f32x4 acc_o[4];
#pragma unroll
    for (int dd = 0; dd < 4; ++dd) acc_o[dd] = (f32x4){0.f, 0.f, 0.f, 0.f};

    const unsigned short* sptr = srow;
    us8 s0 = *(const us8*)sptr;
    us8 s1 = *(const us8*)(sptr + 8);
    sptr += sstep;

    for (int kb = 0; kb < nkv; ++kb) {
      int k0 = kb * 64;
      __syncthreads();  // readers of tile kb-1 (or prior half) done
      if (stageV) {
        *(us8*)&vt_lds[r][cb] = s0;
        *(us8*)&vt_lds[r][cb + 8] = s1;
      } else {
        *(us8*)&k_lds[r][cb] = s0;
        *(us8*)&k_lds[r][cb + 8] = s1;
      }
      __syncthreads();  // tile kb visible
      bool more = (kb + 1) < nkv;
      if (more) {
        s0 = *(const us8*)sptr;        // T14: issue next tile's loads early
        s1 = *(const us8*)(sptr + 8);
        sptr += sstep;
      }

      bool full_masked = (k0 > q0w + 15);
      if (!full_masked) {
        f32x4 s[4];
#pragma unroll
        for (int nf = 0; nf < 4; ++nf) s[nf] = (f32x4){0.f, 0.f, 0.f, 0.f};
        __builtin_amdgcn_s_setprio(1);
#pragma unroll
        for (int nf = 0; nf < 4; ++nf) {
          bf16x8 kf0 = *(const bf16x8*)&k_lds[nf * 16 + l15][lg * 8];
          bf16x8 kf1 = *(const bf16x8*)&k_lds[nf * 16 + l15][32 + lg * 8];
          s[nf] = __builtin_amdgcn_mfma_f32_16x16x32_bf16(qf0, kf0, s[nf], 0, 0, 0);
          s[nf] = __builtin_amdgcn_mfma_f32_16x16x32_bf16(qf1, kf1, s[nf], 0, 0, 0);
        }
        __builtin_amdgcn_s_setprio(0);

        bool diag = (k0 + 63 > q0w);
        if (diag) {
#pragma unroll
          for (int nf = 0; nf < 4; ++nf)
#pragma unroll
            for (int rr = 0; rr < 4; ++rr) {
              int qrow = q0w + lg * 4 + rr;
              int kcol = k0 + nf * 16 + l15;
              float x = (kcol > qrow) ? -1e10f : s[nf][rr];
              float p = __builtin_amdgcn_exp2f(x);
              p_lds[w][lg * 4 + rr][nf * 16 + l15] =
                  (unsigned short)(__builtin_bit_cast(unsigned int, p) >> 16);
            }
        } else {
#pragma unroll
          for (int nf = 0; nf < 4; ++nf)
#pragma unroll
            for (int rr = 0; rr < 4; ++rr) {
              float p = __builtin_amdgcn_exp2f(s[nf][rr]);
              p_lds[w][lg * 4 + rr][nf * 16 + l15] =
                  (unsigned short)(__builtin_bit_cast(unsigned int, p) >> 16);
            }
        }

        __builtin_amdgcn_s_setprio(1);
#pragma unroll
        for (int kk = 0; kk < 2; ++kk) {
          bf16x8 pf = *(const bf16x8*)&p_lds[w][l15][kk * 32 + lg * 8];
          acc_l = __builtin_amdgcn_mfma_f32_16x16x32_bf16(pf, ones, acc_l, 0, 0, 0);
#pragma unroll
          for (int dd = 0; dd < 4; ++dd) {
            bf16x8 vf = *(const bf16x8*)&vt_lds[dd * 16 + l15][kk * 32 + lg * 8];
            acc_o[dd] = __builtin_amdgcn_mfma_f32_16x16x32_bf16(pf, vf, acc_o[dd], 0, 0, 0);
          }
        }
        __builtin_amdgcn_s_setprio(0);
      }
    }

#pragma unroll
    for (int rr = 0; rr < 4; ++rr) {
      float inv = 1.0f / acc_l[rr];
      int qrow = q0 + w * 16 + lg * 4 + rr;
      unsigned short* op = Op + ((size_t)(b * S_LEN + qrow)) * D_MODEL + h * DEPTH;
#pragma unroll
      for (int dd = 0; dd < 4; ++dd)
        op[dd * 16 + l15] = f2bf(acc_o[dd][rr] * inv);
    }
  }
}

// ---------------------------------------------------------------------------
extern "C" void kernel_launch(void* const* d_in, const int* in_sizes, int n_in,
                              void* d_out, int out_size, void* d_ws, size_t ws_size,
                              hipStream_t stream) {
  const float* q  = (const float*)d_in[0];
  const float* v  = (const float*)d_in[1];
  const float* k  = (const float*)d_in[2];
  const float* Wq = (const float*)d_in[3];
  const float* bq = (const float*)d_in[4];
  const float* Wk = (const float*)d_in[5];
  const float* bk = (const float*)d_in[6];
  const float* Wv = (const float*)d_in[7];
  const float* bv = (const float*)d_in[8];
  const float* Wo = (const float*)d_in[9];
  const float* bo = (const float*)d_in[10];

  char* ws = (char*)d_ws;
  const size_t WSZ = (size_t)D_MODEL * D_MODEL * 2;        // 2 MB per weight
  const size_t XSZ = (size_t)BATCH * S_LEN * D_MODEL * 2;  // 16 MB per activation
  unsigned short* Wqt = (unsigned short*)(ws);
  unsigned short* Wkt = (unsigned short*)(ws + WSZ);
  unsigned short* Wvt = (unsigned short*)(ws + 2 * WSZ);
  unsigned short* Wot = (unsigned short*)(ws + 3 * WSZ);
  char* act = ws + 4 * WSZ;
  unsigned short* qb  = (unsigned short*)(act);            // bf16 q
  unsigned short* kb  = (unsigned short*)(act + XSZ);      // bf16 k
  unsigned short* vb  = (unsigned short*)(act + 2 * XSZ);  // bf16 v
  unsigned short* Qp  = (unsigned short*)(act + 3 * XSZ);
  // Aliases (each region dead before its next writer):
  unsigned short* Kp  = qb;   // written by K-GEMM (qb dead after Q-GEMM)
  unsigned short* Vp  = kb;   // written by V-GEMM (kb dead after K-GEMM)
  unsigned short* Vtp = vb;   // written by transpose_v (vb dead after V-GEMM)
  unsigned short* AO  = kb;   // written by attn (Vp=kb dead after transpose_v)
  // total ws use: 8 MB weights + 64 MB activations = 72 MB (same as r9)

  const float SCL = 0.125f * 1.4426950408889634f;
  const int M = BATCH * S_LEN;

  TCArgs tc{};
  tc.W[0] = Wq;  tc.Wt[0] = Wqt;  tc.scale[0] = SCL;
  tc.W[1] = Wk;  tc.Wt[1] = Wkt;  tc.scale[1] = 1.0f;
  tc.W[2] = Wv;  tc.Wt[2] = Wvt;  tc.scale[2] = 1.0f;
  tc.W[3] = Wo;  tc.Wt[3] = Wot;  tc.scale[3] = 1.0f;
  hipLaunchKernelGGL(transpose_cast4, dim3(D_MODEL / 32, D_MODEL / 32, 4), dim3(32, 8),
                     0, stream, tc, D_MODEL);

  hipLaunchKernelGGL(cast3_bf16, dim3(4096), dim3(256), 0, stream, q, k, v, qb, kb, vb);

  hipLaunchKernelGGL((gemm8<false>), dim3(256), dim3(512), 0, stream,
                     qb, Wqt, bq, SCL, (void*)Qp, M, D_MODEL, D_MODEL);
  hipLaunchKernelGGL((gemm8<false>), dim3(256), dim3(512), 0, stream,
                     kb, Wkt, bk, 1.0f, (void*)Kp, M, D_MODEL, D_MODEL);
  hipLaunchKernelGGL((gemm8<false>), dim3(256), dim3(512), 0, stream,
                     vb, Wvt, bv, 1.0f, (void*)Vp, M, D_MODEL, D_MODEL);

  hipLaunchKernelGGL(transpose_v, dim3(S_LEN / 64, BATCH * N_HEADS), dim3(256), 0, stream,
                     Vp, Vtp);

  hipLaunchKernelGGL(attn_kernel, dim3(512), dim3(512), 0, stream, Qp, Kp, Vtp, AO);

  hipLaunchKernelGGL((gemm8<true>), dim3(256), dim3(512), 0, stream,
                     AO, Wot, bo, 1.0f, d_out, M, D_MODEL, D_MODEL);
}

// Round 13
// 188.247 us; speedup vs baseline: 1.1554x; 1.1554x over previous
//
#include <hip/hip_runtime.h>
#include <hip/hip_bf16.h>
#include <cstdint>
#include <cstddef>

#define S_LEN 2048
#define D_MODEL 1024
#define N_HEADS 16
#define DEPTH 64
#define BATCH 4

#define GLOBAL_AS __attribute__((address_space(1)))
#define LDS_AS __attribute__((address_space(3)))

typedef __attribute__((ext_vector_type(4))) float f32x4;
typedef __attribute__((ext_vector_type(8))) short bf16x8;
typedef __attribute__((ext_vector_type(4))) unsigned short us4;
typedef __attribute__((ext_vector_type(8))) unsigned short us8;

__device__ __forceinline__ unsigned short f2bf(float f) {
  unsigned int u = __builtin_bit_cast(unsigned int, f);
  u += 0x7FFFu + ((u >> 16) & 1u);   // round-to-nearest-even
  return (unsigned short)(u >> 16);
}

__device__ __forceinline__ unsigned short f2bf_hw(float f) {
  return __builtin_bit_cast(unsigned short, __float2bfloat16(f));
}

// ---------------------------------------------------------------------------
// Fused weight transpose + scale + fp32 -> bf16 cast for all 4 weights.
// ---------------------------------------------------------------------------
struct TCArgs {
  const float* W[4];
  unsigned short* Wt[4];
  float scale[4];
};

__global__ __launch_bounds__(256) void transpose_cast4(TCArgs a, int N) {
  __shared__ float tile[32][33];
  int z = blockIdx.z;
  const float* W = a.W[z];
  unsigned short* Wt = a.Wt[z];
  float scale = a.scale[z];
  int bx = blockIdx.x * 32;
  int by = blockIdx.y * 32;
  int tx = threadIdx.x, ty = threadIdx.y;  // 32 x 8
#pragma unroll
  for (int i = 0; i < 4; ++i)
    tile[ty + i * 8][tx] = W[(size_t)(by + ty + i * 8) * N + bx + tx];
  __syncthreads();
#pragma unroll
  for (int i = 0; i < 4; ++i)
    Wt[(size_t)(bx + ty + i * 8) * N + by + tx] = f2bf(tile[tx][ty + i * 8] * scale);
}

// ---------------------------------------------------------------------------
// Per-head V transpose: Vp [B,S,D] bf16 -> Vt [B*H][DEPTH][S] bf16
// ---------------------------------------------------------------------------
__global__ __launch_bounds__(256) void transpose_v(const unsigned short* __restrict__ Vp,
                                                   unsigned short* __restrict__ Vt) {
  __shared__ unsigned short tile[64][72];
  int tid = threadIdx.x;
  int sb = blockIdx.x;
  int bh = blockIdx.y;
  int b = bh >> 4, h = bh & 15;
  int s0 = sb * 64;
#pragma unroll
  for (int rep = 0; rep < 2; ++rep) {
    int idx = rep * 256 + tid;
    int r = idx >> 3, c8 = idx & 7;
    us8 v = *(const us8*)(Vp + (size_t)(b * S_LEN + s0 + r) * D_MODEL + h * DEPTH + c8 * 8);
#pragma unroll
    for (int e = 0; e < 8; ++e) tile[c8 * 8 + e][r] = v[e];
  }
  __syncthreads();
#pragma unroll
  for (int rep = 0; rep < 2; ++rep) {
    int idx = rep * 256 + tid;
    int d = idx >> 3, c8 = idx & 7;
    us8 v = *(const us8*)&tile[d][c8 * 8];
    *(us8*)(Vt + ((size_t)(bh * DEPTH + d)) * S_LEN + s0 + c8 * 8) = v;
  }
}

// ---------------------------------------------------------------------------
// GEMM:  C[M][N] = A[M][K] @ Bt[N][K]^T + bias*bscale
// r9's proven 2-barrier reg/glds-staged loop, upgraded to BM=256 x BN=128
// with 8 waves (4M x 2N, 512 thr): 256 MFMAs per barrier-pair instead of
// 128 — halves the barrier-drain tax per FLOP (the binding constraint per
// r11's 8-phase experiment), with NO extra cast pass (fp32 A converted
// inline during reg staging) and NO per-phase barrier tax. T14 register
// prefetch of tile k+1 for reg-staged operands; bf16-A (AO) via
// global_load_lds with XOR-swizzled source + matching read XOR.
// No min-waves bound anywhere (r6/r8: silent spill catastrophes).
// ---------------------------------------------------------------------------
struct GemmSlice {
  const void* A;
  const unsigned short* Bt;
  const float* bias;
  void* C;
  float bscale;
};
struct GemmArgs {
  GemmSlice s[3];
};

template <bool A_IS_F32, bool OUT_F32>
__global__ __launch_bounds__(512) void gemm_bt(GemmArgs args, int M, int N, int K) {
  constexpr int ASTR = A_IS_F32 ? 72 : 64;   // fp32 path: padded; glds path: linear
  constexpr int BSTR = 72;
  __shared__ unsigned short a_lds[256 * ASTR];
  __shared__ unsigned short b_lds[128 * BSTR];

  int slice = blockIdx.y >> 3;
  int nj = blockIdx.y & 7;
  const GemmSlice& g = args.s[slice];
  const float* Af = (const float*)g.A;
  const unsigned short* Ah = (const unsigned short*)g.A;
  const unsigned short* Bt = g.Bt;

  int tid = threadIdx.x;
  int wave = tid >> 6, lane = tid & 63;
  int l15 = lane & 15, lg = lane >> 4;
  int wm = wave >> 1, wn = wave & 1;   // 4M x 2N

  int row0 = blockIdx.x * 256;
  int col0 = nj * 128;

  f32x4 acc[4][4] = {};
  f32x4 av[8];   // in-flight A tile (fp32 path): 256x64 f32 / 512 thr
  us8 bv[2];     // in-flight B tile: 128x64 bf16 / 512 thr

  int ar = tid >> 4, ac4 = tid & 15;  // fp32-A: 32 rows x 16x4 cols per rep
  int br = tid >> 3, bc8 = tid & 7;   // B: 64 rows x 8x8 cols per rep

  auto loadA = [&](int k0) {
#pragma unroll
    for (int rep = 0; rep < 8; ++rep)
      av[rep] = *(const f32x4*)(Af + (size_t)(row0 + rep * 32 + ar) * K + k0 + ac4 * 4);
  };
  auto writeA = [&]() {
#pragma unroll
    for (int rep = 0; rep < 8; ++rep) {
      us4 h = {f2bf_hw(av[rep][0]), f2bf_hw(av[rep][1]),
               f2bf_hw(av[rep][2]), f2bf_hw(av[rep][3])};
      *(us4*)&a_lds[(rep * 32 + ar) * 72 + ac4 * 4] = h;
    }
  };
  auto loadB = [&](int k0) {
#pragma unroll
    for (int rep = 0; rep < 2; ++rep)
      bv[rep] = *(const us8*)(Bt + (size_t)(col0 + rep * 64 + br) * K + k0 + bc8 * 8);
  };
  auto writeB = [&]() {
#pragma unroll
    for (int rep = 0; rep < 2; ++rep)
      *(us8*)&b_lds[(rep * 64 + br) * BSTR + bc8 * 8] = bv[rep];
  };
  auto issueA = [&](int k0) {  // bf16-A via glds, swizzled source (256x64)
#pragma unroll
    for (int rep = 0; rep < 4; ++rep) {
      int chunk = rep * 512 + tid;
      int row = chunk >> 3;
      int c8 = (chunk & 7) ^ (row & 7);
      __builtin_amdgcn_global_load_lds(
          (const GLOBAL_AS void*)(Ah + (size_t)(row0 + row) * K + k0 + c8 * 8),
          (LDS_AS void*)(&a_lds[chunk * 8]), 16, 0, 0);
    }
  };
  auto compute = [&]() {
#pragma unroll
    for (int kk = 0; kk < 2; ++kk) {
      bf16x8 af[4], bfr[4];
#pragma unroll
      for (int ii = 0; ii < 4; ++ii) {
        int row = wm * 64 + ii * 16 + l15;
        if constexpr (A_IS_F32)
          af[ii] = *(const bf16x8*)&a_lds[row * 72 + kk * 32 + lg * 8];
        else
          af[ii] = *(const bf16x8*)&a_lds[row * 64 + (((kk * 4 + lg) ^ (l15 & 7)) * 8)];
      }
#pragma unroll
      for (int jj = 0; jj < 4; ++jj) {
        int row = wn * 64 + jj * 16 + l15;
        bfr[jj] = *(const bf16x8*)&b_lds[row * BSTR + kk * 32 + lg * 8];
      }
#pragma unroll
      for (int ii = 0; ii < 4; ++ii)
#pragma unroll
        for (int jj = 0; jj < 4; ++jj)
          acc[ii][jj] = __builtin_amdgcn_mfma_f32_16x16x32_bf16(af[ii], bfr[jj], acc[ii][jj], 0, 0, 0);
    }
  };

  int nk = K >> 6;
  loadB(0);
  if constexpr (A_IS_F32) loadA(0);

  for (int ki = 0; ki < nk; ++ki) {
    __syncthreads();  // readers of previous tile done
    writeB();
    if constexpr (A_IS_F32)
      writeA();
    else
      issueA(ki * 64);
    __syncthreads();  // tile visible (drains lgkm + vmcnt)
    if (ki + 1 < nk) {
      loadB((ki + 1) * 64);                    // T14: prefetch next tile's regs —
      if constexpr (A_IS_F32) loadA((ki + 1) * 64);  // latency hides under 256 MFMAs
    }
    compute();
  }

  // ---- epilogue ----
#pragma unroll
  for (int ii = 0; ii < 4; ++ii) {
#pragma unroll
    for (int jj = 0; jj < 4; ++jj) {
      int col = col0 + wn * 64 + jj * 16 + l15;
      float bv2 = g.bias[col] * g.bscale;
#pragma unroll
      for (int r = 0; r < 4; ++r) {
        int row = row0 + wm * 64 + ii * 16 + lg * 4 + r;
        float v = acc[ii][jj][r] + bv2;
        if constexpr (OUT_F32)
          ((float*)g.C)[(size_t)row * N + col] = v;
        else
          ((unsigned short*)g.C)[(size_t)row * N + col] = f2bf(v);
      }
    }
  }
}

// ---------------------------------------------------------------------------
// Causal flash attention (byte-identical to the r9/r11 form — thrice
// measured ~71.6us under rocprof). Q pre-scaled by 0.125*log2(e); NO-MAX
// exp2 softmax; l via ones-MFMA. Single-buffered K/V^T, two barriers/step,
// T14 reg prefetch. Plain bounds (r8 spill lesson).
// ---------------------------------------------------------------------------
__global__ __launch_bounds__(512) void attn_kernel(const unsigned short* __restrict__ Qp,
                                                   const unsigned short* __restrict__ Kp,
                                                   const unsigned short* __restrict__ Vt,
                                                   unsigned short* __restrict__ Op) {
  __shared__ unsigned short k_lds[64][76];
  __shared__ unsigned short vt_lds[64][76];   // [d][k]
  __shared__ unsigned short p_lds[8][16][76];

  int tid = threadIdx.x;
  int w = tid >> 6, lane = tid & 63;
  int l15 = lane & 15, lg = lane >> 4;

  int bid = blockIdx.x;                    // 0..511
  int swz = (bid & 7) * 64 + (bid >> 3);   // bijective (512 % 8 == 0)
  int pairIdx = swz & 7;                   // 0..7
  int bh = swz >> 3;                       // 0..63 (8 bh per XCD)
  int b = bh >> 4, h = bh & 15;

  const unsigned short* Kbase = Kp + (size_t)b * S_LEN * D_MODEL + h * DEPTH;
  const unsigned short* Vbase = Vt + (size_t)bh * DEPTH * S_LEN;

  bool stageV = (tid >= 256);
  int st = tid & 255;
  int r = st >> 2, cb = (st & 3) * 16;
  const unsigned short* srow = stageV ? (Vbase + (size_t)r * S_LEN + cb)
                                      : (Kbase + (size_t)r * D_MODEL + cb);
  const size_t sstep = stageV ? 64 : (size_t)64 * D_MODEL;

  bf16x8 ones;
#pragma unroll
  for (int e = 0; e < 8; ++e) ones[e] = (short)0x3F80;

  for (int half = 0; half < 2; ++half) {
    int t = (half == 0) ? pairIdx : (15 - pairIdx);
    int q0 = t * 128;
    int nkv = 2 * t + 2;
    int q0w = q0 + w * 16;

    const unsigned short* qp =
        Qp + ((size_t)(b * S_LEN + q0 + w * 16 + l15)) * D_MODEL + h * DEPTH;
    bf16x8 qf0 = *(const bf16x8*)(qp + lg * 8);
    bf16x8 qf1 = *(const bf16x8*)(qp + 32 + lg * 8);

    f32x4 acc_l = (f32x4){0.f, 0.f, 0.f, 0.f};
    f32x4 acc_o[4];
#pragma unroll
    for (int dd = 0; dd < 4; ++dd) acc_o[dd] = (f32x4){0.f, 0.f, 0.f, 0.f};

    const unsigned short* sptr = srow;
    us8 s0 = *(const us8*)sptr;
    us8 s1 = *(const us8*)(sptr + 8);
    sptr += sstep;

    for (int kb = 0; kb < nkv; ++kb) {
      int k0 = kb * 64;
      __syncthreads();  // readers of tile kb-1 (or prior half) done
      if (stageV) {
        *(us8*)&vt_lds[r][cb] = s0;
        *(us8*)&vt_lds[r][cb + 8] = s1;
      } else {
        *(us8*)&k_lds[r][cb] = s0;
        *(us8*)&k_lds[r][cb + 8] = s1;
      }
      __syncthreads();  // tile kb visible
      bool more = (kb + 1) < nkv;
      if (more) {
        s0 = *(const us8*)sptr;        // T14: issue next tile's loads early
        s1 = *(const us8*)(sptr + 8);
        sptr += sstep;
      }

      bool full_masked = (k0 > q0w + 15);
      if (!full_masked) {
        f32x4 s[4];
#pragma unroll
        for (int nf = 0; nf < 4; ++nf) s[nf] = (f32x4){0.f, 0.f, 0.f, 0.f};
        __builtin_amdgcn_s_setprio(1);
#pragma unroll
        for (int nf = 0; nf < 4; ++nf) {
          bf16x8 kf0 = *(const bf16x8*)&k_lds[nf * 16 + l15][lg * 8];
          bf16x8 kf1 = *(const bf16x8*)&k_lds[nf * 16 + l15][32 + lg * 8];
          s[nf] = __builtin_amdgcn_mfma_f32_16x16x32_bf16(qf0, kf0, s[nf], 0, 0, 0);
          s[nf] = __builtin_amdgcn_mfma_f32_16x16x32_bf16(qf1, kf1, s[nf], 0, 0, 0);
        }
        __builtin_amdgcn_s_setprio(0);

        bool diag = (k0 + 63 > q0w);
        if (diag) {
#pragma unroll
          for (int nf = 0; nf < 4; ++nf)
#pragma unroll
            for (int rr = 0; rr < 4; ++rr) {
              int qrow = q0w + lg * 4 + rr;
              int kcol = k0 + nf * 16 + l15;
              float x = (kcol > qrow) ? -1e10f : s[nf][rr];
              float p = __builtin_amdgcn_exp2f(x);
              p_lds[w][lg * 4 + rr][nf * 16 + l15] =
                  (unsigned short)(__builtin_bit_cast(unsigned int, p) >> 16);
            }
        } else {
#pragma unroll
          for (int nf = 0; nf < 4; ++nf)
#pragma unroll
            for (int rr = 0; rr < 4; ++rr) {
              float p = __builtin_amdgcn_exp2f(s[nf][rr]);
              p_lds[w][lg * 4 + rr][nf * 16 + l15] =
                  (unsigned short)(__builtin_bit_cast(unsigned int, p) >> 16);
            }
        }

        __builtin_amdgcn_s_setprio(1);
#pragma unroll
        for (int kk = 0; kk < 2; ++kk) {
          bf16x8 pf = *(const bf16x8*)&p_lds[w][l15][kk * 32 + lg * 8];
          acc_l = __builtin_amdgcn_mfma_f32_16x16x32_bf16(pf, ones, acc_l, 0, 0, 0);
#pragma unroll
          for (int dd = 0; dd < 4; ++dd) {
            bf16x8 vf = *(const bf16x8*)&vt_lds[dd * 16 + l15][kk * 32 + lg * 8];
            acc_o[dd] = __builtin_amdgcn_mfma_f32_16x16x32_bf16(pf, vf, acc_o[dd], 0, 0, 0);
          }
        }
        __builtin_amdgcn_s_setprio(0);
      }
    }

#pragma unroll
    for (int rr = 0; rr < 4; ++rr) {
      float inv = 1.0f / acc_l[rr];
      int qrow = q0 + w * 16 + lg * 4 + rr;
      unsigned short* op = Op + ((size_t)(b * S_LEN + qrow)) * D_MODEL + h * DEPTH;
#pragma unroll
      for (int dd = 0; dd < 4; ++dd)
        op[dd * 16 + l15] = f2bf(acc_o[dd][rr] * inv);
    }
  }
}

// ---------------------------------------------------------------------------
extern "C" void kernel_launch(void* const* d_in, const int* in_sizes, int n_in,
                              void* d_out, int out_size, void* d_ws, size_t ws_size,
                              hipStream_t stream) {
  const float* q  = (const float*)d_in[0];
  const float* v  = (const float*)d_in[1];
  const float* k  = (const float*)d_in[2];
  const float* Wq = (const float*)d_in[3];
  const float* bq = (const float*)d_in[4];
  const float* Wk = (const float*)d_in[5];
  const float* bk = (const float*)d_in[6];
  const float* Wv = (const float*)d_in[7];
  const float* bv = (const float*)d_in[8];
  const float* Wo = (const float*)d_in[9];
  const float* bo = (const float*)d_in[10];

  char* ws = (char*)d_ws;
  const size_t WSZ = (size_t)D_MODEL * D_MODEL * 2;        // 2 MB per weight
  const size_t XSZ = (size_t)BATCH * S_LEN * D_MODEL * 2;  // 16 MB per activation
  unsigned short* Wqt = (unsigned short*)(ws);
  unsigned short* Wkt = (unsigned short*)(ws + WSZ);
  unsigned short* Wvt = (unsigned short*)(ws + 2 * WSZ);
  unsigned short* Wot = (unsigned short*)(ws + 3 * WSZ);
  unsigned short* Qp  = (unsigned short*)(ws + 4 * WSZ);
  unsigned short* Kp  = (unsigned short*)(ws + 4 * WSZ + XSZ);
  unsigned short* Vp  = (unsigned short*)(ws + 4 * WSZ + 2 * XSZ);
  unsigned short* Vtp = (unsigned short*)(ws + 4 * WSZ + 3 * XSZ);
  unsigned short* AO  = Vp;  // alias: Vp fully consumed by transpose_v before attn writes AO

  const float SCL = 0.125f * 1.4426950408889634f;
  const int M = BATCH * S_LEN;

  TCArgs tc{};
  tc.W[0] = Wq;  tc.Wt[0] = Wqt;  tc.scale[0] = SCL;
  tc.W[1] = Wk;  tc.Wt[1] = Wkt;  tc.scale[1] = 1.0f;
  tc.W[2] = Wv;  tc.Wt[2] = Wvt;  tc.scale[2] = 1.0f;
  tc.W[3] = Wo;  tc.Wt[3] = Wot;  tc.scale[3] = 1.0f;
  hipLaunchKernelGGL(transpose_cast4, dim3(D_MODEL / 32, D_MODEL / 32, 4), dim3(32, 8),
                     0, stream, tc, D_MODEL);

  GemmArgs qkv{};
  qkv.s[0] = GemmSlice{(const void*)q, Wqt, bq, (void*)Qp, SCL};
  qkv.s[1] = GemmSlice{(const void*)k, Wkt, bk, (void*)Kp, 1.0f};
  qkv.s[2] = GemmSlice{(const void*)v, Wvt, bv, (void*)Vp, 1.0f};
  hipLaunchKernelGGL((gemm_bt<true, false>), dim3(M / 256, 24), dim3(512), 0, stream,
                     qkv, M, D_MODEL, D_MODEL);

  hipLaunchKernelGGL(transpose_v, dim3(S_LEN / 64, BATCH * N_HEADS), dim3(256), 0, stream,
                     Vp, Vtp);

  hipLaunchKernelGGL(attn_kernel, dim3(512), dim3(512), 0, stream, Qp, Kp, Vtp, AO);

  GemmArgs ao{};
  ao.s[0] = GemmSlice{(const void*)AO, Wot, bo, d_out, 1.0f};
  hipLaunchKernelGGL((gemm_bt<false, true>), dim3(M / 256, 8), dim3(512), 0, stream,
                     ao, M, D_MODEL, D_MODEL);
}